// Round 3
// baseline (716.236 us; speedup 1.0000x reference)
//
#include <hip/hip_runtime.h>
#include <stdint.h>
#include <stddef.h>

typedef __attribute__((ext_vector_type(8))) short bf16x8;
typedef __attribute__((ext_vector_type(4))) float f32x4;
typedef unsigned short u16;
typedef unsigned int u32;

static __device__ __forceinline__ u16 f2bf(float f) {
    u32 u = __builtin_bit_cast(u32, f);
    u = u + 0x7FFFu + ((u >> 16) & 1u);
    return (u16)(u >> 16);
}
static __device__ __forceinline__ float bf2f(u16 h) {
    return __builtin_bit_cast(float, (u32)h << 16);
}

typedef const __attribute__((address_space(1))) u32* gas1_t;
typedef __attribute__((address_space(3))) u32* las3_t;
static __device__ __forceinline__ void gload_lds16(const void* g, void* l) {
    __builtin_amdgcn_global_load_lds((gas1_t)g, (las3_t)l, 16, 0, 0);
}

// ---------------- fp32 -> bf16 convert (vectorized) ----------------
__global__ __launch_bounds__(256) void k_cvt(const float* __restrict__ s,
                                             u16* __restrict__ d, int n) {
    int i = (blockIdx.x * 256 + threadIdx.x) * 4;
    if (i >= n) return;
    float4 f = *(const float4*)(s + i);
    ushort4 o;
    o.x = f2bf(f.x); o.y = f2bf(f.y); o.z = f2bf(f.z); o.w = f2bf(f.w);
    *(ushort4*)(d + i) = o;
}

// ---------------- GEMM: C(MxN) = A(MxK) * B(NxK)^T, bf16 in, bf16/f32 out ----
// 128x128 tile, BK=64, 4 waves (2x2 of 64x64), 16x16x32 bf16 MFMA.
// LDS tiles row-major [128 rows][128 bytes], XOR-swizzled via pre-swizzled
// global source (global_load_lds writes linearly; read applies same XOR).
template <bool F32OUT>
__global__ __launch_bounds__(256) void k_gemm_bt(const u16* __restrict__ A,
                                                 const u16* __restrict__ B,
                                                 void* __restrict__ Cv,
                                                 int M, int N, int K) {
    __shared__ alignas(16) unsigned char sA[16384];
    __shared__ alignas(16) unsigned char sB[16384];
    const int tid = threadIdx.x;
    const int lane = tid & 63;
    const int wid = tid >> 6;
    const int l15 = lane & 15, l4 = lane >> 4;
    const int brow = blockIdx.y * 128;
    const int bcol = blockIdx.x * 128;
    const int wr = wid >> 1, wc = wid & 1;

    f32x4 acc[4][4];
#pragma unroll
    for (int m = 0; m < 4; ++m)
#pragma unroll
        for (int n = 0; n < 4; ++n) acc[m][n] = (f32x4){0.f, 0.f, 0.f, 0.f};

    const int pbase = wid * 4096 + lane * 16;
    const int nk = K >> 6;
    for (int kt = 0; kt < nk; ++kt) {
        __syncthreads();
#pragma unroll
        for (int i = 0; i < 4; ++i) {
            const int p = pbase + i * 1024;     // byte pos in 16KB tile
            const int row = p >> 7;             // 128B per row (64 bf16)
            const int colb = (p & 127) ^ ((row & 7) << 4);
            const char* gA = (const char*)(A + (size_t)(brow + row) * K + (kt << 6)) + colb;
            const char* gB = (const char*)(B + (size_t)(bcol + row) * K + (kt << 6)) + colb;
            gload_lds16(gA, sA + wid * 4096 + i * 1024);
            gload_lds16(gB, sB + wid * 4096 + i * 1024);
        }
        __syncthreads();
#pragma unroll
        for (int kk = 0; kk < 2; ++kk) {
            bf16x8 af[4], bfr[4];
#pragma unroll
            for (int m = 0; m < 4; ++m) {
                const int row = wr * 64 + m * 16 + l15;
                const int colb = (kk * 64 + l4 * 16) ^ ((row & 7) << 4);
                af[m] = *(const bf16x8*)(sA + row * 128 + colb);
            }
#pragma unroll
            for (int n = 0; n < 4; ++n) {
                const int row = wc * 64 + n * 16 + l15;
                const int colb = (kk * 64 + l4 * 16) ^ ((row & 7) << 4);
                bfr[n] = *(const bf16x8*)(sB + row * 128 + colb);
            }
#pragma unroll
            for (int m = 0; m < 4; ++m)
#pragma unroll
                for (int n = 0; n < 4; ++n)
                    acc[m][n] = __builtin_amdgcn_mfma_f32_16x16x32_bf16(
                        af[m], bfr[n], acc[m][n], 0, 0, 0);
        }
    }
#pragma unroll
    for (int m = 0; m < 4; ++m)
#pragma unroll
        for (int n = 0; n < 4; ++n)
#pragma unroll
            for (int q = 0; q < 4; ++q) {
                const int row = brow + wr * 64 + m * 16 + l4 * 4 + q;
                const int col = bcol + wc * 64 + n * 16 + l15;
                if constexpr (F32OUT)
                    ((float*)Cv)[(size_t)row * N + col] = acc[m][n][q];
                else
                    ((u16*)Cv)[(size_t)row * N + col] = f2bf(acc[m][n][q]);
            }
}

// ---------------- RoPE (in-place on bf16 q and k-part of kv) ----------------
// thread -> (s, hh, d); hh<32: q head hh; hh>=32: k head hh-32. pairs (d, d+64).
__global__ __launch_bounds__(256) void k_rope(u16* __restrict__ q,
                                              u16* __restrict__ kv,
                                              const float* __restrict__ cosb,
                                              const float* __restrict__ sinb) {
    int i = blockIdx.x * 256 + threadIdx.x;
    int s = i / 2560;          // 40 heads * 64 dims
    int rem = i - s * 2560;
    int hh = rem >> 6;
    int d = rem & 63;
    float c = cosb[s * 128 + d];
    float sn = sinb[s * 128 + d];
    u16* p = (hh < 32) ? (q + (size_t)s * 4096 + hh * 128 + d)
                       : (kv + (size_t)s * 2048 + (hh - 32) * 128 + d);
    float a = bf2f(p[0]);
    float b = bf2f(p[64]);
    p[0]  = f2bf(a * c - b * sn);
    p[64] = f2bf(b * c + a * sn);
}

// ---------------- KV-cache scatter: kvnew[sel[s]] = roped kv row s -----------
__global__ __launch_bounds__(256) void k_scatter(const u16* __restrict__ kv,
                                                 const int* __restrict__ sel,
                                                 float* __restrict__ kvnew) {
    int i = blockIdx.x * 256 + threadIdx.x;
    int row = i >> 9;                 // 512 x 4-elem chunks per 2048-row
    int c4 = (i & 511) << 2;
    int r = sel[row];
    ushort4 v = *(const ushort4*)(kv + (size_t)row * 2048 + c4);
    float4 f;
    f.x = bf2f(v.x); f.y = bf2f(v.y); f.z = bf2f(v.z); f.w = bf2f(v.w);
    *(float4*)(kvnew + (size_t)r * 2048 + c4) = f;
}

// ---------------- Flash attention (causal, GQA rep=4) -----------------------
// block = (head, 64 q-rows), 4 waves x 16 rows. K/V tiles 64x128 bf16 staged
// via swizzled global_load_lds. Online softmax in C-fragment layout.
__global__ __launch_bounds__(256) void k_attn(const u16* __restrict__ Q,
                                              const u16* __restrict__ KV,
                                              u16* __restrict__ Oa, int S) {
    __shared__ alignas(16) unsigned char sQ[16384];
    __shared__ alignas(16) unsigned char sK[16384];
    __shared__ alignas(16) unsigned char sV[16384];
    __shared__ alignas(16) unsigned char sP[4 * 16 * 160];  // per-wave 16x80 bf16
    const int tid = threadIdx.x;
    const int lane = tid & 63;
    const int w = tid >> 6;
    const int l15 = lane & 15, l4 = lane >> 4;
    const int h = blockIdx.x;      // q head
    const int q0 = blockIdx.y * 64;
    const int hk = h >> 2;         // kv head (rep=4)

    {
        const int pb = w * 4096 + lane * 16;
#pragma unroll
        for (int i = 0; i < 4; ++i) {
            const int p = pb + i * 1024;
            const int row = p >> 8;                       // 256B rows (128 bf16)
            const int colb = (p & 255) ^ ((row & 7) << 4);
            const char* g = (const char*)(Q + (size_t)(q0 + row) * 4096 + h * 128) + colb;
            gload_lds16(g, sQ + w * 4096 + i * 1024);
        }
    }
    __syncthreads();
    bf16x8 qf[4];
    {
        const int row = w * 16 + l15;
#pragma unroll
        for (int kk = 0; kk < 4; ++kk) {
            const int colb = (kk * 64 + l4 * 16) ^ ((row & 7) << 4);
            qf[kk] = *(const bf16x8*)(sQ + row * 256 + colb);
        }
    }
    float mrow[4] = {-1e30f, -1e30f, -1e30f, -1e30f};
    float lrow[4] = {0.f, 0.f, 0.f, 0.f};
    f32x4 oacc[8];
#pragma unroll
    for (int dn = 0; dn < 8; ++dn) oacc[dn] = (f32x4){0.f, 0.f, 0.f, 0.f};

    const float scale = 0.08838834764831845f;  // 1/sqrt(128)
    const int ntiles = (q0 >> 6) + 1;
    for (int t = 0; t < ntiles; ++t) {
        const int kv0 = t << 6;
        __syncthreads();
        {
            const int pb = w * 4096 + lane * 16;
#pragma unroll
            for (int i = 0; i < 4; ++i) {
                const int p = pb + i * 1024;
                const int row = p >> 8;
                const int colb = (p & 255) ^ ((row & 7) << 4);
                const char* gk = (const char*)(KV + (size_t)(kv0 + row) * 2048 + hk * 128) + colb;
                const char* gv = (const char*)(KV + (size_t)(kv0 + row) * 2048 + 1024 + hk * 128) + colb;
                gload_lds16(gk, sK + w * 4096 + i * 1024);
                gload_lds16(gv, sV + w * 4096 + i * 1024);
            }
        }
        __syncthreads();
        // QK^T: 16 rows x 64 keys per wave
        f32x4 sf[4];
#pragma unroll
        for (int n = 0; n < 4; ++n) {
            sf[n] = (f32x4){0.f, 0.f, 0.f, 0.f};
#pragma unroll
            for (int kk = 0; kk < 4; ++kk) {
                const int row = n * 16 + l15;
                const int colb = (kk * 64 + l4 * 16) ^ ((row & 7) << 4);
                bf16x8 kf = *(const bf16x8*)(sK + row * 256 + colb);
                sf[n] = __builtin_amdgcn_mfma_f32_16x16x32_bf16(qf[kk], kf, sf[n], 0, 0, 0);
            }
        }
        const bool diag = (kv0 == q0);
#pragma unroll
        for (int n = 0; n < 4; ++n)
#pragma unroll
            for (int q = 0; q < 4; ++q) {
                float v = sf[n][q] * scale;
                if (diag) {
                    const int col = n * 16 + l15;
                    const int rowq = w * 16 + l4 * 4 + q;
                    if (col > rowq) v = -1e9f;
                }
                sf[n][q] = v;
            }
        float al[4], rsum[4];
#pragma unroll
        for (int q = 0; q < 4; ++q) {
            float m0 = fmaxf(fmaxf(sf[0][q], sf[1][q]), fmaxf(sf[2][q], sf[3][q]));
#pragma unroll
            for (int d = 1; d < 16; d <<= 1) m0 = fmaxf(m0, __shfl_xor(m0, d));
            const float mn = fmaxf(mrow[q], m0);
            al[q] = __expf(mrow[q] - mn);
            mrow[q] = mn;
            rsum[q] = 0.f;
        }
#pragma unroll
        for (int n = 0; n < 4; ++n)
#pragma unroll
            for (int q = 0; q < 4; ++q) {
                float p = __expf(sf[n][q] - mrow[q]);
                sf[n][q] = p;
                rsum[q] += p;
            }
#pragma unroll
        for (int q = 0; q < 4; ++q) {
#pragma unroll
            for (int d = 1; d < 16; d <<= 1) rsum[q] += __shfl_xor(rsum[q], d);
            lrow[q] = lrow[q] * al[q] + rsum[q];
        }
#pragma unroll
        for (int dn = 0; dn < 8; ++dn) {
            oacc[dn][0] *= al[0]; oacc[dn][1] *= al[1];
            oacc[dn][2] *= al[2]; oacc[dn][3] *= al[3];
        }
        // P (16x64) -> LDS (pitch 80 elems), then read back as A-fragments
        {
            u16* pw = (u16*)(sP + w * 2560);
#pragma unroll
            for (int n = 0; n < 4; ++n)
#pragma unroll
                for (int q = 0; q < 4; ++q)
                    pw[(l4 * 4 + q) * 80 + n * 16 + l15] = f2bf(sf[n][q]);
        }
#pragma unroll
        for (int kk2 = 0; kk2 < 2; ++kk2) {
            bf16x8 pf = *(const bf16x8*)(sP + w * 2560 + l15 * 160 + kk2 * 64 + l4 * 16);
#pragma unroll
            for (int dn = 0; dn < 8; ++dn) {
                bf16x8 vf;
#pragma unroll
                for (int j = 0; j < 8; ++j) {
                    const int k = kk2 * 32 + l4 * 8 + j;
                    const int byteoff = k * 256 + ((dn * 32 + l15 * 2) ^ ((k & 7) << 4));
                    vf[j] = (short)*(const u16*)(sV + byteoff);
                }
                oacc[dn] = __builtin_amdgcn_mfma_f32_16x16x32_bf16(pf, vf, oacc[dn], 0, 0, 0);
            }
        }
    }
#pragma unroll
    for (int dn = 0; dn < 8; ++dn)
#pragma unroll
        for (int q = 0; q < 4; ++q) {
            const int row = q0 + w * 16 + l4 * 4 + q;
            const int col = h * 128 + dn * 16 + l15;
            Oa[(size_t)row * 4096 + col] = f2bf(oacc[dn][q] / lrow[q]);
        }
}

extern "C" void kernel_launch(void* const* d_in, const int* in_sizes, int n_in,
                              void* d_out, int out_size, void* d_ws, size_t ws_size,
                              hipStream_t stream) {
    (void)n_in; (void)out_size; (void)ws_size;
    const float* x    = (const float*)d_in[0];
    const float* cosb = (const float*)d_in[1];
    const float* sinb = (const float*)d_in[2];
    const float* wq   = (const float*)d_in[3];
    const float* wkv  = (const float*)d_in[4];
    const float* wo   = (const float*)d_in[5];
    const int*   sel  = (const int*)d_in[6];
    const float* kvbuf = (const float*)d_in[7];

    const int H = 4096, HKV = 2048;
    const int S = in_sizes[0] / H;      // 2048
    const int MT = in_sizes[7] / HKV;   // 8192

    // Workspace layout (peak 88 MiB; lifetimes disjoint where aliased):
    //   [ 0, 16) xb   : x in bf16            — dead after kv-GEMM
    //   [ 0, 16) attnb: attention output     — aliases xb (written after)
    //   [16, 48) wqb  : wq in bf16           — dead after q-GEMM
    //   [16, 48) wob  : wo in bf16           — aliases wqb (converted after)
    //   [48, 64) wkvb : w_kv in bf16
    //   [64, 80) qb   : q (roped)
    //   [80, 88) kvb  : k|v (k roped)
    char* ws = (char*)d_ws;
    u16* xb    = (u16*)(ws);
    u16* attnb = (u16*)(ws);
    u16* wqb   = (u16*)(ws + (16u << 20));
    u16* wob   = (u16*)(ws + (16u << 20));
    u16* wkvb  = (u16*)(ws + (48u << 20));
    u16* qb    = (u16*)(ws + (64u << 20));
    u16* kvb   = (u16*)(ws + (80u << 20));

    float* out = (float*)d_out;              // S x H
    float* kvnew = out + (size_t)S * H;      // MT x HKV

    const int nx = S * H, nwq = H * H, nwkv = HKV * H, nwo = H * H;
    k_cvt<<<nx / 1024, 256, 0, stream>>>(x, xb, nx);
    k_cvt<<<nwq / 1024, 256, 0, stream>>>(wq, wqb, nwq);
    k_cvt<<<nwkv / 1024, 256, 0, stream>>>(wkv, wkvb, nwkv);

    k_gemm_bt<false><<<dim3(H / 128, S / 128), 256, 0, stream>>>(xb, wqb, qb, S, H, H);
    k_gemm_bt<false><<<dim3(HKV / 128, S / 128), 256, 0, stream>>>(xb, wkvb, kvb, S, HKV, H);

    // wq dead -> reuse its slot for wo; x dead -> attnb aliases xb.
    k_cvt<<<nwo / 1024, 256, 0, stream>>>(wo, wob, nwo);

    k_rope<<<(S * 2560) / 256, 256, 0, stream>>>(qb, kvb, cosb, sinb);

    hipMemcpyAsync(kvnew, kvbuf, (size_t)MT * HKV * sizeof(float),
                   hipMemcpyDeviceToDevice, stream);
    k_scatter<<<(S * HKV / 4) / 256, 256, 0, stream>>>(kvb, sel, kvnew);

    k_attn<<<dim3(32, S / 64), 256, 0, stream>>>(qb, kvb, attnb, S);

    k_gemm_bt<true><<<dim3(H / 128, S / 128), 256, 0, stream>>>(attnb, wob, out, S, H, H);
}